// Round 4
// baseline (1107.842 us; speedup 1.0000x reference)
//
#include <hip/hip_runtime.h>
#include <hip/hip_bf16.h>

#define BHn 32
#define Nn 2048
#define Dn 64
#define KSEL 30
#define CAP 112
#define RB 128  // rows per block
#define CT 64   // cols per k-tile
#define ZTH 1.80f

typedef short bf16x8 __attribute__((ext_vector_type(8)));
typedef float f32x4 __attribute__((ext_vector_type(4)));
typedef unsigned long long u64;

__device__ __forceinline__ unsigned ford(float x) {
  unsigned b = __float_as_uint(x);
  return (b & 0x80000000u) ? ~b : (b | 0x80000000u);
}
__device__ __forceinline__ float unford(unsigned u) {
  unsigned b = (u & 0x80000000u) ? (u & 0x7fffffffu) : ~u;
  return __uint_as_float(b);
}
__device__ __forceinline__ u64 umax64(u64 a, u64 b) { return a > b ? a : b; }

// packed split: x = hi(bf16) + lo(bf16)
__device__ __forceinline__ void split2(float a, float b, ushort2& hi, ushort2& lo) {
  __hip_bfloat162 h = __float22bfloat162_rn(make_float2(a, b));
  union { __hip_bfloat162 v; ushort2 u; } ch; ch.v = h;
  hi = ch.u;
  float2 hf = __bfloat1622float2(h);
  __hip_bfloat162 l = __float22bfloat162_rn(make_float2(a - hf.x, b - hf.y));
  union { __hip_bfloat162 v; ushort2 u; } cl; cl.v = l;
  lo = cl.u;
}

// ================= fused: scores -> topk -> softmax -> attn + ctx =================
__global__ __launch_bounds__(256, 2) void fused_attn(
    const float* __restrict__ q, const float* __restrict__ k,
    const float* __restrict__ v, float* __restrict__ ctx,
    float* __restrict__ attn, u64* __restrict__ cand,
    unsigned* __restrict__ flags) {
  __shared__ ushort qh[RB][64], ql[RB][64];  // 32 KB
  __shared__ ushort kh[CT][64], kl[CT][64];  // 16 KB
  __shared__ unsigned ccnt[RB];
  __shared__ float tf[RB];
  __shared__ u64 scr[4][CAP];                // epilogue scratch, per wave

  const int t = threadIdx.x;
  const int bid = blockIdx.x;
  // XCD swizzle: 4 consecutive heads per XCD (k,v L2-resident)
  const int bh = (bid & 7) * 4 + ((bid >> 3) & 3);
  const int rb = bid >> 5;
  const int lane = t & 63, w = t >> 6;
  const int m16 = lane & 15, quad = lane >> 4;

  const float* qb = q + ((size_t)bh * Nn + rb * RB) * Dn;
  const float* kb = k + (size_t)bh * Nn * Dn;
  const size_t growbase = (size_t)bh * Nn + (size_t)rb * RB;

  // stage q row-block, split bf16 hi/lo, XOR-swizzled chunks
#pragma unroll
  for (int i = 0; i < 8; ++i) {
    int c = t + 256 * i;
    int row = c >> 4, f4 = c & 15;
    float4 a = *(const float4*)(qb + row * Dn + f4 * 4);
    int sp = (((f4 >> 1) ^ (row & 7)) << 1) | (f4 & 1);
    ushort2 h0, l0, h1, l1;
    split2(a.x, a.y, h0, l0);
    split2(a.z, a.w, h1, l1);
    *(ushort4*)&qh[row][sp * 4] = make_ushort4(h0.x, h0.y, h1.x, h1.y);
    *(ushort4*)&ql[row][sp * 4] = make_ushort4(l0.x, l0.y, l1.x, l1.y);
  }
  // per-row threshold T = z*||q_row|| (scores | q ~ iid N(0, ||q||^2))
  if (t < RB) {
    const float* qr = qb + t * Dn;
    float ss = 0.f;
#pragma unroll
    for (int i = 0; i < 16; ++i) {
      float4 a = *(const float4*)(qr + i * 4);
      ss = fmaf(a.x, a.x, ss); ss = fmaf(a.y, a.y, ss);
      ss = fmaf(a.z, a.z, ss); ss = fmaf(a.w, a.w, ss);
    }
    tf[t] = ZTH * sqrtf(ss);
    ccnt[t] = 0u;
  }
  __syncthreads();

  // per-lane threshold keys for the 8 rows this lane's acc registers own
  unsigned tfr[2][4];
#pragma unroll
  for (int mt = 0; mt < 2; ++mt)
#pragma unroll
    for (int rg = 0; rg < 4; ++rg)
      tfr[mt][rg] = ford(tf[w * 32 + mt * 16 + quad * 4 + rg]);

  for (int ct = 0; ct < Nn / CT; ++ct) {
    __syncthreads();  // prior MFMA reads of kh/kl done before restage
    // stage k tile (64 cols x 64 dims)
#pragma unroll
    for (int i = 0; i < 4; ++i) {
      int c = t + 256 * i;
      int row = c >> 4, f4 = c & 15;
      float4 a = *(const float4*)(kb + (size_t)(ct * CT + row) * Dn + f4 * 4);
      int sp = (((f4 >> 1) ^ (row & 7)) << 1) | (f4 & 1);
      ushort2 h0, l0, h1, l1;
      split2(a.x, a.y, h0, l0);
      split2(a.z, a.w, h1, l1);
      *(ushort4*)&kh[row][sp * 4] = make_ushort4(h0.x, h0.y, h1.x, h1.y);
      *(ushort4*)&kl[row][sp * 4] = make_ushort4(l0.x, l0.y, l1.x, l1.y);
    }
    // dense zero-store of this attn tile (value-independent; overlaps MFMA)
#pragma unroll
    for (int i = 0; i < 8; ++i) {
      int c = t + 256 * i;
      int row = c >> 4, f4c = c & 15;
      *(float4*)(attn + (growbase + row) * Nn + ct * CT + f4c * 4) =
          make_float4(0.f, 0.f, 0.f, 0.f);
    }
    __syncthreads();

    f32x4 acc[2][4];
#pragma unroll
    for (int mt = 0; mt < 2; ++mt)
#pragma unroll
      for (int nt = 0; nt < 4; ++nt) acc[mt][nt] = (f32x4){0.f, 0.f, 0.f, 0.f};

#pragma unroll
    for (int ks = 0; ks < 2; ++ks) {
      bf16x8 aH[2], aL[2], bH[4], bL[4];
#pragma unroll
      for (int mt = 0; mt < 2; ++mt) {
        int r = w * 32 + mt * 16 + m16;
        int ch = (ks * 4 + quad) ^ (r & 7);
        aH[mt] = *(const bf16x8*)&qh[r][ch * 8];
        aL[mt] = *(const bf16x8*)&ql[r][ch * 8];
      }
#pragma unroll
      for (int nt = 0; nt < 4; ++nt) {
        int rr = nt * 16 + m16;
        int ch = (ks * 4 + quad) ^ (rr & 7);
        bH[nt] = *(const bf16x8*)&kh[rr][ch * 8];
        bL[nt] = *(const bf16x8*)&kl[rr][ch * 8];
      }
#pragma unroll
      for (int mt = 0; mt < 2; ++mt)
#pragma unroll
        for (int nt = 0; nt < 4; ++nt) {
          acc[mt][nt] = __builtin_amdgcn_mfma_f32_16x16x32_bf16(aL[mt], bH[nt], acc[mt][nt], 0, 0, 0);
          acc[mt][nt] = __builtin_amdgcn_mfma_f32_16x16x32_bf16(aH[mt], bL[nt], acc[mt][nt], 0, 0, 0);
          acc[mt][nt] = __builtin_amdgcn_mfma_f32_16x16x32_bf16(aH[mt], bH[nt], acc[mt][nt], 0, 0, 0);
        }
    }

    // candidate append: ford(s) > T_row -> global side list
#pragma unroll
    for (int mt = 0; mt < 2; ++mt)
#pragma unroll
      for (int rg = 0; rg < 4; ++rg) {
        unsigned tk = tfr[mt][rg];
        int rl = w * 32 + mt * 16 + quad * 4 + rg;
#pragma unroll
        for (int nt = 0; nt < 4; ++nt) {
          float s = acc[mt][nt][rg];
          unsigned fk = ford(s);
          if (fk > tk) {
            unsigned pos = atomicAdd(&ccnt[rl], 1u);
            if (pos < CAP) {
              int col = ct * CT + nt * 16 + m16;
              cand[(growbase + rl) * CAP + pos] =
                  ((u64)fk << 32) | (unsigned)(2047 - col);  // tie-break: col asc
            }
          }
        }
      }
  }
  __syncthreads();  // all zero-stores + cand writes drained

  // ---- epilogue: wave w handles rows [w*32, w*32+32) ----
  u64* sw_ = scr[w];
  for (int i = 0; i < 32; ++i) {
    int rl = w * 32 + i;
    size_t gr = growbase + rl;
    int C = (int)ccnt[rl];
    bool bad = (C < KSEL) || (C > CAP);
    if (lane == 0) flags[gr] = bad ? 1u : 0u;
    if (bad) continue;  // repair kernel finishes this row

    for (int p = lane; p < C; p += 64) sw_[p] = cand[gr * CAP + p];

    const int slots = (C + 63) >> 6;  // 1 or 2
    u64 mykey[2] = {0ull, 0ull};
    int rk[2] = {CAP, CAP};
    float es[2] = {0.f, 0.f};
    u64 mymax = 0ull;
#pragma unroll
    for (int tt = 0; tt < 2; ++tt) {
      if (tt < slots) {
        int p = lane + 64 * tt;
        mykey[tt] = (p < C) ? sw_[p] : 0ull;
        mymax = umax64(mymax, mykey[tt]);
      }
    }
#pragma unroll
    for (int off = 32; off; off >>= 1) mymax = umax64(mymax, __shfl_xor(mymax, off));
    const float mrow = unford((unsigned)(mymax >> 32));

#pragma unroll 1
    for (int tt = 0; tt < slots; ++tt) {
      int r = 0;
      u64 me = mykey[tt];
      for (int jj = 0; jj < C; ++jj) r += (sw_[jj] > me);
      rk[tt] = r;
    }
    float z = 0.f;
#pragma unroll
    for (int tt = 0; tt < 2; ++tt) {
      int p = lane + 64 * tt;
      bool sel = (tt < slots) && (p < C) && (rk[tt] < KSEL);
      es[tt] = sel ? __expf(unford((unsigned)(mykey[tt] >> 32)) - mrow) : 0.f;
      z += es[tt];
    }
#pragma unroll
    for (int off = 32; off; off >>= 1) z += __shfl_xor(z, off);
    const float invZ = 1.f / z;

#pragma unroll
    for (int tt = 0; tt < 2; ++tt) {
      int p = lane + 64 * tt;
      if (tt < slots && p < C && rk[tt] < KSEL) {
        float wv = es[tt] * invZ;
        int col = 2047 - (int)(mykey[tt] & 0xffffffffu);
        sw_[rk[tt]] = ((u64)__float_as_uint(wv) << 32) | (unsigned)col;
        attn[gr * Nn + col] = wv;  // zeros already written; scatter weights
      }
    }
    const float* vb = v + (size_t)bh * Nn * Dn;
    float a = 0.f;
#pragma unroll
    for (int p = 0; p < KSEL; ++p) {
      u64 e = sw_[p];
      a = fmaf(__uint_as_float((unsigned)(e >> 32)), vb[(e & 0x7ffull) * Dn + lane], a);
    }
    ctx[gr * Dn + lane] = a;
  }
}

// ============ repair: exact per-row path for statistically-flagged rows ============
__global__ __launch_bounds__(256) void repair_rows(
    const float* __restrict__ q, const float* __restrict__ k,
    const float* __restrict__ v, float* __restrict__ ctx,
    float* __restrict__ attn, const unsigned* __restrict__ flags) {
  __shared__ float sc2[Nn];  // 8 KB
  __shared__ u64 red[256];
  __shared__ float qrow[Dn];
  __shared__ int selc[KSEL];
  __shared__ float selv[KSEL];
  __shared__ float zsh;
  __shared__ unsigned flagbuf[256];

  const int t = threadIdx.x;
  const int base = blockIdx.x * 256;
  flagbuf[t] = flags[base + t];
  __syncthreads();

  for (int i = 0; i < 256; ++i) {
    if (flagbuf[i] == 0u) continue;
    const int gr = base + i;
    const int bh = gr >> 11;
    if (t < Dn) qrow[t] = q[(size_t)gr * Dn + t];
    __syncthreads();
    const float* kb = k + (size_t)bh * Nn * Dn;
#pragma unroll
    for (int j = 0; j < 8; ++j) {
      int col = t + 256 * j;
      float s = 0.f;
      for (int d = 0; d < Dn; d += 4) {
        float4 kk = *(const float4*)(kb + (size_t)col * Dn + d);
        s = fmaf(qrow[d], kk.x, s);
        s = fmaf(qrow[d + 1], kk.y, s);
        s = fmaf(qrow[d + 2], kk.z, s);
        s = fmaf(qrow[d + 3], kk.w, s);
      }
      sc2[col] = s;
    }
    __syncthreads();
    for (int p = 0; p < KSEL; ++p) {
      u64 best = 0ull;
#pragma unroll
      for (int j = 0; j < 8; ++j) {
        int col = t + 256 * j;
        u64 kk = ((u64)ford(sc2[col]) << 32) | (unsigned)(2047 - col);
        best = umax64(best, kk);
      }
      red[t] = best;
      __syncthreads();
      for (int off = 128; off; off >>= 1) {
        if (t < off) red[t] = umax64(red[t], red[t + off]);
        __syncthreads();
      }
      if (t == 0) {
        u64 b = red[0];
        int col = 2047 - (int)(b & 0xffffffffu);
        selc[p] = col;
        selv[p] = unford((unsigned)(b >> 32));
        sc2[col] = -3.4e38f;
      }
      __syncthreads();
    }
    if (t == 0) {
      float m = selv[0], zz = 0.f;
      for (int p = 0; p < KSEL; ++p) zz += __expf(selv[p] - m);
      zsh = 1.f / zz;
    }
    __syncthreads();
    if (t < KSEL) attn[(size_t)gr * Nn + selc[t]] = __expf(selv[t] - selv[0]) * zsh;
    if (t < Dn) {
      const float* vb = v + (size_t)bh * Nn * Dn;
      float a = 0.f;
      for (int p = 0; p < KSEL; ++p)
        a = fmaf(__expf(selv[p] - selv[0]) * zsh, vb[(size_t)selc[p] * Dn + t], a);
      ctx[(size_t)gr * Dn + t] = a;
    }
    __syncthreads();
  }
}

extern "C" void kernel_launch(void* const* d_in, const int* in_sizes, int n_in,
                              void* d_out, int out_size, void* d_ws,
                              size_t ws_size, hipStream_t stream) {
  const float* q = (const float*)d_in[0];
  const float* k = (const float*)d_in[1];
  const float* v = (const float*)d_in[2];
  float* out = (float*)d_out;
  float* ctx = out;                           // [32,2048,64]
  float* attn = out + (size_t)BHn * Nn * Dn;  // [32,2048,2048]

  unsigned* flags = (unsigned*)d_ws;                       // 256 KB
  u64* cand = (u64*)((char*)d_ws + (size_t)BHn * Nn * 4);  // 58.7 MB

  fused_attn<<<dim3(BHn * Nn / RB), 256, 0, stream>>>(q, k, v, ctx, attn, cand, flags);
  repair_rows<<<dim3(BHn * Nn / 256), 256, 0, stream>>>(q, k, v, ctx, attn, flags);
}

// Round 5
// 860.803 us; speedup vs baseline: 1.2870x; 1.2870x over previous
//
#include <hip/hip_runtime.h>
#include <hip/hip_bf16.h>

#define BHn 32
#define Nn 2048
#define Dn 64
#define KSEL 30
#define CAP 112
#define RB 128  // rows per compute block
#define CT 64   // cols per k-tile
#define ZTH 1.80f

typedef short bf16x8 __attribute__((ext_vector_type(8)));
typedef float f32x4 __attribute__((ext_vector_type(4)));
typedef unsigned long long u64;

__device__ __forceinline__ unsigned ford(float x) {
  unsigned b = __float_as_uint(x);
  return (b & 0x80000000u) ? ~b : (b | 0x80000000u);
}
__device__ __forceinline__ float unford(unsigned u) {
  unsigned b = (u & 0x80000000u) ? (u & 0x7fffffffu) : ~u;
  return __uint_as_float(b);
}
__device__ __forceinline__ u64 umax64(u64 a, u64 b) { return a > b ? a : b; }

// packed split: x = hi(bf16) + lo(bf16)
__device__ __forceinline__ void split2(float a, float b, ushort2& hi, ushort2& lo) {
  __hip_bfloat162 h = __float22bfloat162_rn(make_float2(a, b));
  union { __hip_bfloat162 v; ushort2 u; } ch; ch.v = h;
  hi = ch.u;
  float2 hf = __bfloat1622float2(h);
  __hip_bfloat162 l = __float22bfloat162_rn(make_float2(a - hf.x, b - hf.y));
  union { __hip_bfloat162 v; ushort2 u; } cl; cl.v = l;
  lo = cl.u;
}

// ====== K1: MFMA scores + threshold candidate append (no dense stores) ======
__global__ __launch_bounds__(256, 3) void score_cand(
    const float* __restrict__ q, const float* __restrict__ k,
    u64* __restrict__ cand, unsigned* __restrict__ counts) {
  __shared__ ushort qh[RB][64], ql[RB][64];  // 32 KB
  __shared__ ushort kh[CT][64], kl[CT][64];  // 16 KB
  __shared__ unsigned ccnt[RB];
  __shared__ float tf[RB];

  const int t = threadIdx.x;
  const int bid = blockIdx.x;
  // XCD swizzle: 4 heads per XCD -> k,v L2-resident (4 x 512 KB = 2 MB/XCD)
  const int bh = (bid & 7) * 4 + ((bid >> 3) & 3);
  const int rb = bid >> 5;
  const int lane = t & 63, w = t >> 6;
  const int m16 = lane & 15, quad = lane >> 4;

  const float* qb = q + ((size_t)bh * Nn + rb * RB) * Dn;
  const float* kb = k + (size_t)bh * Nn * Dn;
  const size_t growbase = (size_t)bh * Nn + (size_t)rb * RB;

#pragma unroll
  for (int i = 0; i < 8; ++i) {
    int c = t + 256 * i;
    int row = c >> 4, f4 = c & 15;
    float4 a = *(const float4*)(qb + row * Dn + f4 * 4);
    int sp = (((f4 >> 1) ^ (row & 7)) << 1) | (f4 & 1);
    ushort2 h0, l0, h1, l1;
    split2(a.x, a.y, h0, l0);
    split2(a.z, a.w, h1, l1);
    *(ushort4*)&qh[row][sp * 4] = make_ushort4(h0.x, h0.y, h1.x, h1.y);
    *(ushort4*)&ql[row][sp * 4] = make_ushort4(l0.x, l0.y, l1.x, l1.y);
  }
  // per-row threshold T = z*||q_row||  (scores | q ~ iid N(0, ||q||^2))
  if (t < RB) {
    const float* qr = qb + t * Dn;
    float ss = 0.f;
#pragma unroll
    for (int i = 0; i < 16; ++i) {
      float4 a = *(const float4*)(qr + i * 4);
      ss = fmaf(a.x, a.x, ss); ss = fmaf(a.y, a.y, ss);
      ss = fmaf(a.z, a.z, ss); ss = fmaf(a.w, a.w, ss);
    }
    tf[t] = ZTH * sqrtf(ss);
    ccnt[t] = 0u;
  }
  __syncthreads();

  unsigned tfr[2][4];
#pragma unroll
  for (int mt = 0; mt < 2; ++mt)
#pragma unroll
    for (int rg = 0; rg < 4; ++rg)
      tfr[mt][rg] = ford(tf[w * 32 + mt * 16 + quad * 4 + rg]);

  for (int ct = 0; ct < Nn / CT; ++ct) {
    __syncthreads();
#pragma unroll
    for (int i = 0; i < 4; ++i) {
      int c = t + 256 * i;
      int row = c >> 4, f4 = c & 15;
      float4 a = *(const float4*)(kb + (size_t)(ct * CT + row) * Dn + f4 * 4);
      int sp = (((f4 >> 1) ^ (row & 7)) << 1) | (f4 & 1);
      ushort2 h0, l0, h1, l1;
      split2(a.x, a.y, h0, l0);
      split2(a.z, a.w, h1, l1);
      *(ushort4*)&kh[row][sp * 4] = make_ushort4(h0.x, h0.y, h1.x, h1.y);
      *(ushort4*)&kl[row][sp * 4] = make_ushort4(l0.x, l0.y, l1.x, l1.y);
    }
    __syncthreads();

    f32x4 acc[2][4];
#pragma unroll
    for (int mt = 0; mt < 2; ++mt)
#pragma unroll
      for (int nt = 0; nt < 4; ++nt) acc[mt][nt] = (f32x4){0.f, 0.f, 0.f, 0.f};

#pragma unroll
    for (int ks = 0; ks < 2; ++ks) {
      bf16x8 aH[2], aL[2], bH[4], bL[4];
#pragma unroll
      for (int mt = 0; mt < 2; ++mt) {
        int r = w * 32 + mt * 16 + m16;
        int ch = (ks * 4 + quad) ^ (r & 7);
        aH[mt] = *(const bf16x8*)&qh[r][ch * 8];
        aL[mt] = *(const bf16x8*)&ql[r][ch * 8];
      }
#pragma unroll
      for (int nt = 0; nt < 4; ++nt) {
        int rr = nt * 16 + m16;
        int ch = (ks * 4 + quad) ^ (rr & 7);
        bH[nt] = *(const bf16x8*)&kh[rr][ch * 8];
        bL[nt] = *(const bf16x8*)&kl[rr][ch * 8];
      }
#pragma unroll
      for (int mt = 0; mt < 2; ++mt)
#pragma unroll
        for (int nt = 0; nt < 4; ++nt) {
          acc[mt][nt] = __builtin_amdgcn_mfma_f32_16x16x32_bf16(aL[mt], bH[nt], acc[mt][nt], 0, 0, 0);
          acc[mt][nt] = __builtin_amdgcn_mfma_f32_16x16x32_bf16(aH[mt], bL[nt], acc[mt][nt], 0, 0, 0);
          acc[mt][nt] = __builtin_amdgcn_mfma_f32_16x16x32_bf16(aH[mt], bH[nt], acc[mt][nt], 0, 0, 0);
        }
    }

#pragma unroll
    for (int mt = 0; mt < 2; ++mt)
#pragma unroll
      for (int rg = 0; rg < 4; ++rg) {
        unsigned tk = tfr[mt][rg];
        int rl = w * 32 + mt * 16 + quad * 4 + rg;
#pragma unroll
        for (int nt = 0; nt < 4; ++nt) {
          float s = acc[mt][nt][rg];
          unsigned fk = ford(s);
          if (fk > tk) {
            unsigned pos = atomicAdd(&ccnt[rl], 1u);
            if (pos < CAP) {
              int col = ct * CT + nt * 16 + m16;
              cand[(growbase + rl) * CAP + pos] =
                  ((u64)fk << 32) | (unsigned)(2047 - col);  // tie: col asc
            }
          }
        }
      }
  }
  __syncthreads();
  if (t < RB) counts[growbase + t] = ccnt[t];
}

// ====== K2: wave/row exact top-30 + softmax -> compact list + ctx ======
__global__ __launch_bounds__(256) void select_rows(
    u64* __restrict__ cand, const unsigned* __restrict__ counts,
    const float* __restrict__ v, float* __restrict__ ctx,
    unsigned* __restrict__ flags) {
  __shared__ u64 scr[4][CAP];
  const int lane = threadIdx.x & 63, wv = threadIdx.x >> 6;
  const size_t gr = (size_t)blockIdx.x * 4 + wv;
  const int bh = (int)(gr >> 11);

  const int C = (int)counts[gr];
  const bool bad = (C < KSEL) || (C > CAP);
  if (lane == 0) flags[gr] = bad ? 1u : 0u;
  if (bad) return;

  u64* sw_ = scr[wv];
  for (int p = lane; p < C; p += 64) sw_[p] = cand[gr * CAP + p];

  const int slots = (C + 63) >> 6;  // 1 or 2
  u64 mykey[2] = {0ull, 0ull};
  int rk[2] = {CAP, CAP};
  float es[2] = {0.f, 0.f};
  u64 mymax = 0ull;
#pragma unroll
  for (int tt = 0; tt < 2; ++tt) {
    if (tt < slots) {
      int p = lane + 64 * tt;
      mykey[tt] = (p < C) ? sw_[p] : 0ull;
      mymax = umax64(mymax, mykey[tt]);
    }
  }
#pragma unroll
  for (int off = 32; off; off >>= 1) mymax = umax64(mymax, __shfl_xor(mymax, off));
  const float mrow = unford((unsigned)(mymax >> 32));

#pragma unroll 1
  for (int tt = 0; tt < slots; ++tt) {
    int r = 0;
    u64 me = mykey[tt];
    for (int jj = 0; jj < C; ++jj) r += (sw_[jj] > me);
    rk[tt] = r;
  }
  float z = 0.f;
#pragma unroll
  for (int tt = 0; tt < 2; ++tt) {
    int p = lane + 64 * tt;
    bool sel = (tt < slots) && (p < C) && (rk[tt] < KSEL);
    es[tt] = sel ? __expf(unford((unsigned)(mykey[tt] >> 32)) - mrow) : 0.f;
    z += es[tt];
  }
#pragma unroll
  for (int off = 32; off; off >>= 1) z += __shfl_xor(z, off);
  const float invZ = 1.f / z;

#pragma unroll
  for (int tt = 0; tt < 2; ++tt) {
    int p = lane + 64 * tt;
    if (tt < slots && p < C && rk[tt] < KSEL) {
      float wt = es[tt] * invZ;
      unsigned col = 2047u - (unsigned)(mykey[tt] & 0xffffffffu);
      u64 e = ((u64)__float_as_uint(wt) << 32) | col;
      sw_[rk[tt]] = e;
      cand[gr * CAP + rk[tt]] = e;  // compact (w,col) list for fill
    }
  }
  const float* vb = v + (size_t)bh * Nn * Dn;
  float a = 0.f;
#pragma unroll
  for (int p = 0; p < KSEL; ++p) {
    u64 e = sw_[p];
    a = fmaf(__uint_as_float((unsigned)(e >> 32)), vb[(e & 0x7ffull) * Dn + lane], a);
  }
  ctx[gr * Dn + lane] = a;
}

// ====== K3: exact repair for statistically-flagged rows (rare) ======
__global__ __launch_bounds__(256) void repair_rows(
    const float* __restrict__ q, const float* __restrict__ k,
    const float* __restrict__ v, float* __restrict__ ctx,
    u64* __restrict__ cand, const unsigned* __restrict__ flags) {
  __shared__ float sc2[Nn];
  __shared__ u64 red[256];
  __shared__ float qrow[Dn];
  __shared__ int selc[KSEL];
  __shared__ float selv[KSEL];
  __shared__ float zsh;
  __shared__ unsigned flagbuf[256];

  const int t = threadIdx.x;
  const int base = blockIdx.x * 256;
  flagbuf[t] = flags[base + t];
  __syncthreads();

  for (int i = 0; i < 256; ++i) {
    if (flagbuf[i] == 0u) continue;
    const int gr = base + i;
    const int bh = gr >> 11;
    if (t < Dn) qrow[t] = q[(size_t)gr * Dn + t];
    __syncthreads();
    const float* kb = k + (size_t)bh * Nn * Dn;
#pragma unroll
    for (int j = 0; j < 8; ++j) {
      int col = t + 256 * j;
      float s = 0.f;
      for (int d = 0; d < Dn; d += 4) {
        float4 kk = *(const float4*)(kb + (size_t)col * Dn + d);
        s = fmaf(qrow[d], kk.x, s);
        s = fmaf(qrow[d + 1], kk.y, s);
        s = fmaf(qrow[d + 2], kk.z, s);
        s = fmaf(qrow[d + 3], kk.w, s);
      }
      sc2[col] = s;
    }
    __syncthreads();
    for (int p = 0; p < KSEL; ++p) {
      u64 best = 0ull;
#pragma unroll
      for (int j = 0; j < 8; ++j) {
        int col = t + 256 * j;
        u64 kk = ((u64)ford(sc2[col]) << 32) | (unsigned)(2047 - col);
        best = umax64(best, kk);
      }
      red[t] = best;
      __syncthreads();
      for (int off = 128; off; off >>= 1) {
        if (t < off) red[t] = umax64(red[t], red[t + off]);
        __syncthreads();
      }
      if (t == 0) {
        u64 b = red[0];
        int col = 2047 - (int)(b & 0xffffffffu);
        selc[p] = col;
        selv[p] = unford((unsigned)(b >> 32));
        sc2[col] = -3.4e38f;
      }
      __syncthreads();
    }
    if (t == 0) {
      float m = selv[0], zz = 0.f;
      for (int p = 0; p < KSEL; ++p) zz += __expf(selv[p] - m);
      zsh = 1.f / zz;
    }
    __syncthreads();
    if (t < KSEL) {
      float wt = __expf(selv[t] - selv[0]) * zsh;
      cand[(size_t)gr * CAP + t] = ((u64)__float_as_uint(wt) << 32) | (unsigned)selc[t];
    }
    if (t < Dn) {
      const float* vb = v + (size_t)bh * Nn * Dn;
      float a = 0.f;
      for (int p = 0; p < KSEL; ++p)
        a = fmaf(__expf(selv[p] - selv[0]) * zsh, vb[(size_t)selc[p] * Dn + t], a);
      ctx[(size_t)gr * Dn + t] = a;
    }
    __syncthreads();
  }
}

// ====== K4: dense streaming fill of attn (zeros merged with 30 weights/row) ======
__global__ __launch_bounds__(256) void fill_attn(
    const u64* __restrict__ cand, float* __restrict__ attn) {
  __shared__ float lrow[4 * Nn];  // 32 KB
  const int t = threadIdx.x;
  const size_t row0 = (size_t)blockIdx.x * 4;

  // zero LDS (lane-contiguous float4)
#pragma unroll
  for (int i = 0; i < 8; ++i)
    *(float4*)&lrow[i * 1024 + t * 4] = make_float4(0.f, 0.f, 0.f, 0.f);
  __syncthreads();
  // scatter 4 x 30 weights
  if (t < 4 * KSEL) {
    int r = t / KSEL, p = t - r * KSEL;
    u64 e = cand[(row0 + r) * CAP + p];
    lrow[r * Nn + (int)(e & 0x7ffull)] = __uint_as_float((unsigned)(e >> 32));
  }
  __syncthreads();
  // stream out (lane-contiguous float4)
  float* ab = attn + row0 * Nn;
#pragma unroll
  for (int i = 0; i < 8; ++i)
    *(float4*)(ab + i * 1024 + t * 4) = *(const float4*)&lrow[i * 1024 + t * 4];
}

extern "C" void kernel_launch(void* const* d_in, const int* in_sizes, int n_in,
                              void* d_out, int out_size, void* d_ws,
                              size_t ws_size, hipStream_t stream) {
  const float* q = (const float*)d_in[0];
  const float* k = (const float*)d_in[1];
  const float* v = (const float*)d_in[2];
  float* out = (float*)d_out;
  float* ctx = out;                           // [32,2048,64]
  float* attn = out + (size_t)BHn * Nn * Dn;  // [32,2048,2048]

  unsigned* counts = (unsigned*)d_ws;                          // 256 KB
  unsigned* flags = counts + (size_t)BHn * Nn;                 // 256 KB
  u64* cand = (u64*)((char*)d_ws + (size_t)BHn * Nn * 8);      // 58.7 MB

  score_cand<<<dim3(BHn * Nn / RB), 256, 0, stream>>>(q, k, cand, counts);
  select_rows<<<dim3(BHn * Nn / 4), 256, 0, stream>>>(cand, counts, v, ctx, flags);
  repair_rows<<<dim3(BHn * Nn / 256), 256, 0, stream>>>(q, k, v, ctx, cand, flags);
  fill_attn<<<dim3(BHn * Nn / 4), 256, 0, stream>>>(cand, attn);
}

// Round 7
// 803.970 us; speedup vs baseline: 1.3780x; 1.0707x over previous
//
#include <hip/hip_runtime.h>
#include <hip/hip_bf16.h>

#define BHn 32
#define Nn 2048
#define Dn 64
#define KSEL 30
#define CAP 112
#define RB 128  // rows per compute block
#define CT 64   // cols per k-tile
#define ZTH 1.80f

typedef short bf16x8 __attribute__((ext_vector_type(8)));
typedef float f32x4 __attribute__((ext_vector_type(4)));
typedef unsigned long long u64;

__device__ __forceinline__ unsigned ford(float x) {
  unsigned b = __float_as_uint(x);
  return (b & 0x80000000u) ? ~b : (b | 0x80000000u);
}
__device__ __forceinline__ float unford(unsigned u) {
  unsigned b = (u & 0x80000000u) ? (u & 0x7fffffffu) : ~u;
  return __uint_as_float(b);
}
__device__ __forceinline__ u64 umax64(u64 a, u64 b) { return a > b ? a : b; }

// packed split: x = hi(bf16) + lo(bf16)
__device__ __forceinline__ void split2(float a, float b, ushort2& hi, ushort2& lo) {
  __hip_bfloat162 h = __float22bfloat162_rn(make_float2(a, b));
  union { __hip_bfloat162 v; ushort2 u; } ch; ch.v = h;
  hi = ch.u;
  float2 hf = __bfloat1622float2(h);
  __hip_bfloat162 l = __float22bfloat162_rn(make_float2(a - hf.x, b - hf.y));
  union { __hip_bfloat162 v; ushort2 u; } cl; cl.v = l;
  lo = cl.u;
}

// ====== K1: MFMA scores + threshold candidate append (prefetched k staging) ======
__global__ __launch_bounds__(256, 3) void score_cand(
    const float* __restrict__ q, const float* __restrict__ k,
    u64* __restrict__ cand, unsigned* __restrict__ counts) {
  __shared__ ushort qh[RB][64], ql[RB][64];  // 32 KB
  __shared__ ushort kh[CT][64], kl[CT][64];  // 16 KB
  __shared__ unsigned ccnt[RB];
  __shared__ float tf[RB];

  const int t = threadIdx.x;
  const int bid = blockIdx.x;
  // XCD swizzle: 4 heads per XCD -> k L2-resident (4 x 512 KB = 2 MB/XCD)
  const int bh = (bid & 7) * 4 + ((bid >> 3) & 3);
  const int rb = bid >> 5;
  const int lane = t & 63, w = t >> 6;
  const int m16 = lane & 15, quad = lane >> 4;

  const float* qb = q + ((size_t)bh * Nn + rb * RB) * Dn;
  const float* kb = k + (size_t)bh * Nn * Dn;
  const size_t growbase = (size_t)bh * Nn + (size_t)rb * RB;

#pragma unroll
  for (int i = 0; i < 8; ++i) {
    int c = t + 256 * i;
    int row = c >> 4, f4 = c & 15;
    float4 a = *(const float4*)(qb + row * Dn + f4 * 4);
    int sp = (((f4 >> 1) ^ (row & 7)) << 1) | (f4 & 1);
    ushort2 h0, l0, h1, l1;
    split2(a.x, a.y, h0, l0);
    split2(a.z, a.w, h1, l1);
    *(ushort4*)&qh[row][sp * 4] = make_ushort4(h0.x, h0.y, h1.x, h1.y);
    *(ushort4*)&ql[row][sp * 4] = make_ushort4(l0.x, l0.y, l1.x, l1.y);
  }
  // per-row threshold T = z*||q_row||  (scores | q ~ iid N(0, ||q||^2))
  if (t < RB) {
    const float* qr = qb + t * Dn;
    float ss = 0.f;
#pragma unroll
    for (int i = 0; i < 16; ++i) {
      float4 a = *(const float4*)(qr + i * 4);
      ss = fmaf(a.x, a.x, ss); ss = fmaf(a.y, a.y, ss);
      ss = fmaf(a.z, a.z, ss); ss = fmaf(a.w, a.w, ss);
    }
    tf[t] = ZTH * sqrtf(ss);
    ccnt[t] = 0u;
  }

  unsigned tfr[2][4];
  // prefetch k tile 0
  float4 pre[4];
#pragma unroll
  for (int i = 0; i < 4; ++i) {
    int c = t + 256 * i;
    pre[i] = *(const float4*)(kb + (size_t)(c >> 4) * Dn + (c & 15) * 4);
  }
  __syncthreads();

#pragma unroll
  for (int mt = 0; mt < 2; ++mt)
#pragma unroll
    for (int rg = 0; rg < 4; ++rg)
      tfr[mt][rg] = ford(tf[w * 32 + mt * 16 + quad * 4 + rg]);

  for (int ct = 0; ct < Nn / CT; ++ct) {
    // store prefetched tile -> LDS (split bf16 hi/lo, swizzled)
#pragma unroll
    for (int i = 0; i < 4; ++i) {
      int c = t + 256 * i;
      int row = c >> 4, f4 = c & 15;
      float4 a = pre[i];
      int sp = (((f4 >> 1) ^ (row & 7)) << 1) | (f4 & 1);
      ushort2 h0, l0, h1, l1;
      split2(a.x, a.y, h0, l0);
      split2(a.z, a.w, h1, l1);
      *(ushort4*)&kh[row][sp * 4] = make_ushort4(h0.x, h0.y, h1.x, h1.y);
      *(ushort4*)&kl[row][sp * 4] = make_ushort4(l0.x, l0.y, l1.x, l1.y);
    }
    __syncthreads();  // staging visible

    // issue next tile's loads now: they fly during MFMA+append
    if (ct + 1 < Nn / CT) {
#pragma unroll
      for (int i = 0; i < 4; ++i) {
        int c = t + 256 * i;
        pre[i] = *(const float4*)(kb + (size_t)((ct + 1) * CT + (c >> 4)) * Dn + (c & 15) * 4);
      }
    }

    f32x4 acc[2][4];
#pragma unroll
    for (int mt = 0; mt < 2; ++mt)
#pragma unroll
      for (int nt = 0; nt < 4; ++nt) acc[mt][nt] = (f32x4){0.f, 0.f, 0.f, 0.f};

#pragma unroll
    for (int ks = 0; ks < 2; ++ks) {
      bf16x8 aH[2], aL[2], bH[4], bL[4];
#pragma unroll
      for (int mt = 0; mt < 2; ++mt) {
        int r = w * 32 + mt * 16 + m16;
        int ch = (ks * 4 + quad) ^ (r & 7);
        aH[mt] = *(const bf16x8*)&qh[r][ch * 8];
        aL[mt] = *(const bf16x8*)&ql[r][ch * 8];
      }
#pragma unroll
      for (int nt = 0; nt < 4; ++nt) {
        int rr = nt * 16 + m16;
        int ch = (ks * 4 + quad) ^ (rr & 7);
        bH[nt] = *(const bf16x8*)&kh[rr][ch * 8];
        bL[nt] = *(const bf16x8*)&kl[rr][ch * 8];
      }
#pragma unroll
      for (int mt = 0; mt < 2; ++mt)
#pragma unroll
        for (int nt = 0; nt < 4; ++nt) {
          acc[mt][nt] = __builtin_amdgcn_mfma_f32_16x16x32_bf16(aL[mt], bH[nt], acc[mt][nt], 0, 0, 0);
          acc[mt][nt] = __builtin_amdgcn_mfma_f32_16x16x32_bf16(aH[mt], bL[nt], acc[mt][nt], 0, 0, 0);
          acc[mt][nt] = __builtin_amdgcn_mfma_f32_16x16x32_bf16(aH[mt], bH[nt], acc[mt][nt], 0, 0, 0);
        }
    }

#pragma unroll
    for (int mt = 0; mt < 2; ++mt)
#pragma unroll
      for (int rg = 0; rg < 4; ++rg) {
        unsigned tk = tfr[mt][rg];
        int rl = w * 32 + mt * 16 + quad * 4 + rg;
#pragma unroll
        for (int nt = 0; nt < 4; ++nt) {
          float s = acc[mt][nt][rg];
          unsigned fk = ford(s);
          if (fk > tk) {
            unsigned pos = atomicAdd(&ccnt[rl], 1u);
            if (pos < CAP) {
              int col = ct * CT + nt * 16 + m16;
              cand[(growbase + rl) * CAP + pos] =
                  ((u64)fk << 32) | (unsigned)(2047 - col);  // tie: col asc
            }
          }
        }
      }
    __syncthreads();  // MFMA LDS reads done before restage
  }
  if (t < RB) counts[growbase + t] = ccnt[t];
}

// ====== K2: select top-30 + softmax + ctx + dense attn fill (4 rows/block) ======
__global__ __launch_bounds__(256) void select_fill(
    u64* __restrict__ cand, const unsigned* __restrict__ counts,
    const float* __restrict__ v, float* __restrict__ ctx,
    float* __restrict__ attn, unsigned* __restrict__ flags) {
  __shared__ float lrow[4 * Nn];  // 32 KB row images
  __shared__ u64 scr[4][CAP];
  const int t = threadIdx.x;
  const int lane = t & 63, wv = t >> 6;
  const size_t row0 = (size_t)blockIdx.x * 4;
  const size_t gr = row0 + wv;
  const int bh = (int)(gr >> 11);

  // zero the row images
#pragma unroll
  for (int i = 0; i < 8; ++i)
    *(f32x4*)&lrow[i * 1024 + t * 4] = (f32x4){0.f, 0.f, 0.f, 0.f};

  const int C = (int)counts[gr];
  const bool bad = (C < KSEL) || (C > CAP);
  if (lane == 0) flags[gr] = bad ? 1u : 0u;

  if (!bad) {
    u64* sw_ = scr[wv];
    for (int p = lane; p < C; p += 64) sw_[p] = cand[gr * CAP + p];

    const int slots = (C + 63) >> 6;  // 1 or 2
    u64 mykey[2] = {0ull, 0ull};
    int rk[2] = {CAP, CAP};
    float es[2] = {0.f, 0.f};
    u64 mymax = 0ull;
#pragma unroll
    for (int tt = 0; tt < 2; ++tt) {
      if (tt < slots) {
        int p = lane + 64 * tt;
        mykey[tt] = (p < C) ? sw_[p] : 0ull;
        mymax = umax64(mymax, mykey[tt]);
      }
    }
#pragma unroll
    for (int off = 32; off; off >>= 1) mymax = umax64(mymax, __shfl_xor(mymax, off));
    const float mrow = unford((unsigned)(mymax >> 32));

#pragma unroll 1
    for (int tt = 0; tt < slots; ++tt) {
      int r = 0;
      u64 me = mykey[tt];
      for (int jj = 0; jj < C; ++jj) r += (sw_[jj] > me);
      rk[tt] = r;
    }
    float z = 0.f;
#pragma unroll
    for (int tt = 0; tt < 2; ++tt) {
      int p = lane + 64 * tt;
      bool sel = (tt < slots) && (p < C) && (rk[tt] < KSEL);
      es[tt] = sel ? __expf(unford((unsigned)(mykey[tt] >> 32)) - mrow) : 0.f;
      z += es[tt];
    }
#pragma unroll
    for (int off = 32; off; off >>= 1) z += __shfl_xor(z, off);
    const float invZ = 1.f / z;

#pragma unroll
    for (int tt = 0; tt < 2; ++tt) {
      int p = lane + 64 * tt;
      if (tt < slots && p < C && rk[tt] < KSEL) {
        float wt = es[tt] * invZ;
        int col = 2047 - (int)(mykey[tt] & 0xffffffffu);
        u64 e = ((u64)__float_as_uint(wt) << 32) | (unsigned)col;
        sw_[rk[tt]] = e;
        lrow[wv * Nn + col] = wt;  // scatter weight into LDS row image
      }
    }
    // ctx[gr][lane] = sum_p w_p * v[col_p][lane]
    const float* vb = v + (size_t)bh * Nn * Dn;
    float a = 0.f;
#pragma unroll
    for (int p = 0; p < KSEL; ++p) {
      u64 e = sw_[p];
      a = fmaf(__uint_as_float((unsigned)(e >> 32)), vb[(e & 0x7ffull) * Dn + lane], a);
    }
    ctx[gr * Dn + lane] = a;
  }
  __syncthreads();  // zeros + weight scatters visible

  // stream 4 dense rows out, nontemporal (536 MB total; don't pollute L2)
  float* ab = attn + row0 * Nn;
#pragma unroll
  for (int i = 0; i < 8; ++i) {
    f32x4 vv = *(const f32x4*)&lrow[i * 1024 + t * 4];
    __builtin_nontemporal_store(vv, (f32x4*)(ab + i * 1024 + t * 4));
  }
}

// ====== K3: exact repair for statistically-flagged rows (rare) ======
__global__ __launch_bounds__(256) void repair_rows(
    const float* __restrict__ q, const float* __restrict__ k,
    const float* __restrict__ v, float* __restrict__ ctx,
    float* __restrict__ attn, const unsigned* __restrict__ flags) {
  __shared__ float sc2[Nn];
  __shared__ u64 red[256];
  __shared__ float qrow[Dn];
  __shared__ int selc[KSEL];
  __shared__ float selv[KSEL];
  __shared__ float zsh;
  __shared__ unsigned flagbuf[256];

  const int t = threadIdx.x;
  const int base = blockIdx.x * 256;
  flagbuf[t] = flags[base + t];
  __syncthreads();

  for (int i = 0; i < 256; ++i) {
    if (flagbuf[i] == 0u) continue;
    const int gr = base + i;
    const int bh = gr >> 11;
    if (t < Dn) qrow[t] = q[(size_t)gr * Dn + t];
    __syncthreads();
    const float* kb = k + (size_t)bh * Nn * Dn;
#pragma unroll
    for (int j = 0; j < 8; ++j) {
      int col = t + 256 * j;
      float s = 0.f;
      for (int d = 0; d < Dn; d += 4) {
        float4 kk = *(const float4*)(kb + (size_t)col * Dn + d);
        s = fmaf(qrow[d], kk.x, s);
        s = fmaf(qrow[d + 1], kk.y, s);
        s = fmaf(qrow[d + 2], kk.z, s);
        s = fmaf(qrow[d + 3], kk.w, s);
      }
      sc2[col] = s;
    }
    __syncthreads();
    for (int p = 0; p < KSEL; ++p) {
      u64 best = 0ull;
#pragma unroll
      for (int j = 0; j < 8; ++j) {
        int col = t + 256 * j;
        u64 kk = ((u64)ford(sc2[col]) << 32) | (unsigned)(2047 - col);
        best = umax64(best, kk);
      }
      red[t] = best;
      __syncthreads();
      for (int off = 128; off; off >>= 1) {
        if (t < off) red[t] = umax64(red[t], red[t + off]);
        __syncthreads();
      }
      if (t == 0) {
        u64 b = red[0];
        int col = 2047 - (int)(b & 0xffffffffu);
        selc[p] = col;
        selv[p] = unford((unsigned)(b >> 32));
        sc2[col] = -3.4e38f;
      }
      __syncthreads();
    }
    if (t == 0) {
      float m = selv[0], zz = 0.f;
      for (int p = 0; p < KSEL; ++p) zz += __expf(selv[p] - m);
      zsh = 1.f / zz;
    }
    __syncthreads();
    if (t < KSEL)
      attn[(size_t)gr * Nn + selc[t]] = __expf(selv[t] - selv[0]) * zsh;
    if (t < Dn) {
      const float* vb = v + (size_t)bh * Nn * Dn;
      float a = 0.f;
      for (int p = 0; p < KSEL; ++p)
        a = fmaf(__expf(selv[p] - selv[0]) * zsh, vb[(size_t)selc[p] * Dn + t], a);
      ctx[(size_t)gr * Dn + t] = a;
    }
    __syncthreads();
  }
}

extern "C" void kernel_launch(void* const* d_in, const int* in_sizes, int n_in,
                              void* d_out, int out_size, void* d_ws,
                              size_t ws_size, hipStream_t stream) {
  const float* q = (const float*)d_in[0];
  const float* k = (const float*)d_in[1];
  const float* v = (const float*)d_in[2];
  float* out = (float*)d_out;
  float* ctx = out;                           // [32,2048,64]
  float* attn = out + (size_t)BHn * Nn * Dn;  // [32,2048,2048]

  unsigned* counts = (unsigned*)d_ws;                      // 256 KB
  unsigned* flags = counts + (size_t)BHn * Nn;             // 256 KB
  u64* cand = (u64*)((char*)d_ws + (size_t)BHn * Nn * 8);  // 58.7 MB

  score_cand<<<dim3(BHn * Nn / RB), 256, 0, stream>>>(q, k, cand, counts);
  select_fill<<<dim3(BHn * Nn / 4), 256, 0, stream>>>(cand, counts, v, ctx, attn, flags);
  repair_rows<<<dim3(BHn * Nn / 256), 256, 0, stream>>>(q, k, v, ctx, attn, flags);
}